// Round 4
// baseline (216.027 us; speedup 1.0000x reference)
//
#include <hip/hip_runtime.h>

// Fused RK4 step for 2D Burgers-like PDE, periodic BCs, radius-2 stencils.
// R6: bank-perfect LDS geometry.
//  - LCOLS=100 (row stride = 4 banks mod 32) + COLUMN-MAJOR quad ownership
//    (qr = q%80, qc = q/80; 8|80 -> every aligned 8-lane group reads 8
//    consecutive rows at the same qc -> start banks 4*(qr+qc) mod 32 cover all
//    8 f4 slots exactly once -> zero-conflict ds_read_b128/ds_write_b128).
//  - f2 edge reads become 2-way (free, m136). Stores: plain cached f4 (row-
//    scattered across lanes; L2 merges lines -- nontemporal removed).
//  - Staging: async global_load_lds, 32 uniform 1024B chunks per field
//    (8192 floats; 192-float tail staged-but-never-read -> no predicates).
//    LDS = 2 x 32768 B = 64 KiB exactly; 2 blocks/CU retained.
//  - Center-in-register across stages + exact per-stage regions  [R5, valid].
//  - __launch_bounds__(1024,4): VGPR cap 128 (R4's (1024,8) spill lesson).

typedef float f4 __attribute__((ext_vector_type(4)));
typedef float f2 __attribute__((ext_vector_type(2)));

#define LCOLS 100           // output cols at staged cols [16,80)
#define LROWS 80            // output rows at staged rows [8,72)
#define NFLD  8192          // 80*100 = 8000 staged + 192 dead tail (chunk pad)
#define NT    1024
#define NQ    2             // 1600 quads / 1024 threads

#define GLOAD16(gp, lp) __builtin_amdgcn_global_load_lds(                      \
    (const __attribute__((address_space(1))) void*)(gp),                       \
    (__attribute__((address_space(3))) void*)(lp), 16, 0, 0)

__global__ __launch_bounds__(NT, 4)
void rk4_stencil(const float* __restrict__ h,
                 const float* __restrict__ sRe, const float* __restrict__ sUA,
                 const float* __restrict__ sUB, const float* __restrict__ sVA,
                 const float* __restrict__ sVB, float* __restrict__ out)
{
    __shared__ __align__(16) float tu[NFLD];
    __shared__ __align__(16) float tv[NFLD];

    const int tid = threadIdx.x;
    const int tc = blockIdx.x, tr = blockIdx.y, bb = blockIdx.z;

    const float Re = sRe[0], UA = sUA[0], UB = sUB[0], VA = sVA[0], VB = sVB[0];
    const float nu = 0.001f / Re;

    const float d1 = 800.f/12.f;          // (8/12)/DX
    const float d2 = 100.f/12.f;          // (1/12)/DX
    const float a1 = (4.f/3.f)*1.0e4f;    // (4/3)/DX^2
    const float a2 = -(1.f/12.f)*1.0e4f;  // (-1/12)/DX^2
    const float a0 = -5.0e4f;             // -5/DX^2 (both axes center)

    const f4 z4 = {0.f, 0.f, 0.f, 0.f};

    const size_t plane = 1048576;
    const float* uin = h + (size_t)(bb*2) * plane;
    const float* vin = uin + plane;
    const int base_r = tr*64 - 8  + 1024;   // pre-biased for & 1023 wrap
    const int base_c = tc*64 - 16 + 1024;   // multiple of 4 -> no f4 straddle

    // ---- async stage u0,v0: 2 fields x 32 chunks x 1024B, no predicates ----
    // chunk tail (idx >= 8000) stages wrapped-garbage rows 80/81: never read.
    {
        const int wave = tid >> 6, lane = tid & 63;
#pragma unroll
        for (int it = 0; it < 4; ++it) {
            int c = wave + 16*it;           // wave-uniform chunk id 0..63
            int fld = (c >= 32);
            int cc  = c & 31;
            int idx = 256*cc + 4*lane;      // float index into 80x100 tile
            int row = idx / LCOLS;
            int col = idx - row*LCOLS;      // multiple of 4 (idx,100 = 0 mod 4)
            int gr = (base_r + row) & 1023;
            int gc = (base_c + col) & 1023;
            const float* gp = (fld ? vin : uin) + ((size_t)gr << 10) + gc;
            float* lp = (fld ? tv : tu) + 256*cc;   // wave-uniform LDS base
            GLOAD16(gp, lp);
        }
    }
    __syncthreads();   // drains vmcnt -> tile visible

    // ownership (COLUMN-MAJOR): q = tid + NT*j; qr = q%80, qc = q/80 + 2.
    // Aligned 8-lane groups share qc with 8 consecutive qr -> conflict-free.
    int  lidx[NQ]; bool has[NQ]; int qrA[NQ], qcA[NQ];
    f4 ku[NQ], kv[NQ], au[NQ], av[NQ];   // prev-stage k and RK accumulator
    f4 stu[NQ], stv[NQ];                 // t_{s+1} center: LDS-write staging AND
                                         // next stage's in-register center
#pragma unroll
    for (int j = 0; j < NQ; ++j) {
        int q = tid + NT*j;
        has[j] = (j == 0) || (q < 1600);
        int qr = q % 80, qc = q / 80 + 2;
        qrA[j] = qr; qcA[j] = qc;
        lidx[j] = qr*LCOLS + 4*qc;
        ku[j] = z4; kv[j] = z4; au[j] = z4; av[j] = z4;
        stu[j] = z4; stv[j] = z4;
    }

    // exact per-stage regions (output = staged rows [8,72) x cols [16,80)):
    // k1 rows [2,78) qc [2,22); k2 rows [4,76) qc [3,21);
    // k3 rows [6,74) qc [3,21); k4 rows [8,72) qc [4,20)
    // regions shrink monotonically -> register center valid for s>=1.
    const int rowlo[4] = {2, 4, 6, 8};
    const int rowhi[4] = {78, 76, 74, 72};
    const int qclo[4]  = {2, 3, 3, 4};
    const int qchi[4]  = {22, 21, 21, 20};
    const float csub_t[4] = {0.f, 0.25f, 0.25f, 0.5f};  // c_{s-1}: undo prev update
    const float cadd_t[4] = {0.25f, 0.25f, 0.5f, 0.f};  // c_s: apply this update
    const float wgt_t[4]  = {1.f, 2.f, 2.f, 1.f};

    float* outu = out + (size_t)(bb*2) * plane;
    float* outv = outu + plane;

#pragma unroll
    for (int s = 0; s < 4; ++s) {
        const float wgt  = wgt_t[s];
        const float csub = csub_t[s];
        const float cadd = cadd_t[s];
        bool act[NQ];
#pragma unroll
        for (int j = 0; j < NQ; ++j) {
            act[j] = has[j] && qrA[j] >= rowlo[s] && qrA[j] < rowhi[s]
                            && qcA[j] >= qclo[s]  && qcA[j] < qchi[s];
            if (!act[j]) continue;
            const int l = lidx[j];
            f4 ucc, vcc;
            if (s == 0) { ucc = *(const f4*)(tu+l); vcc = *(const f4*)(tv+l); }
            else        { ucc = stu[j];             vcc = stv[j]; }
            f2 ul2 = *(const f2*)(tu+l-2);
            f2 ur2 = *(const f2*)(tu+l+4);
            f4 un1 = *(const f4*)(tu+l-LCOLS);
            f4 us1 = *(const f4*)(tu+l+LCOLS);
            f4 un2 = *(const f4*)(tu+l-2*LCOLS);
            f4 us2 = *(const f4*)(tu+l+2*LCOLS);
            f2 vl2 = *(const f2*)(tv+l-2);
            f2 vr2 = *(const f2*)(tv+l+4);
            f4 vn1 = *(const f4*)(tv+l-LCOLS);
            f4 vs1 = *(const f4*)(tv+l+LCOLS);
            f4 vn2 = *(const f4*)(tv+l-2*LCOLS);
            f4 vs2 = *(const f4*)(tv+l+2*LCOLS);
            float hu[8] = {ul2[0],ul2[1],ucc[0],ucc[1],ucc[2],ucc[3],ur2[0],ur2[1]};
            float hv[8] = {vl2[0],vl2[1],vcc[0],vcc[1],vcc[2],vcc[3],vr2[0],vr2[1]};
            f4 ou, ov;   // stage-3 output staging
#pragma unroll
            for (int k = 0; k < 4; ++k) {
                float u = hu[k+2], v = hv[k+2];
                // row-direction derivative (axis 2) = reference K_DX
                float urow = d1*(us1[k]-un1[k]) + d2*(un2[k]-us2[k]);
                float vrow = d1*(vs1[k]-vn1[k]) + d2*(vn2[k]-vs2[k]);
                // col-direction derivative (axis 3) = reference K_DY
                float ucol = d1*(hu[k+3]-hu[k+1]) + d2*(hu[k]-hu[k+4]);
                float vcol = d1*(hv[k+3]-hv[k+1]) + d2*(hv[k]-hv[k+4]);
                float ulap = a1*((un1[k]+us1[k])+(hu[k+1]+hu[k+3]))
                           + a2*((un2[k]+us2[k])+(hu[k]+hu[k+4])) + a0*u;
                float vlap = a1*((vn1[k]+vs1[k])+(hv[k+1]+hv[k+3]))
                           + a2*((vn2[k]+vs2[k])+(hv[k]+hv[k+4])) + a0*v;
                float fu = nu*ulap + UA*(u*urow) + UB*(v*ucol);
                float fv = nu*vlap + VA*(u*vrow) + VB*(v*vcol);
                float kuold = ku[j][k], kvold = kv[j][k];
                if (s == 3) {
                    // u0 = t3 - DT*k3 ; out = u0 + (DT/6)*(k1+2k2+2k3+k4)
                    ou[k] = (u - 0.5f*kuold) + (1.f/12.f)*(au[j][k] + fu);
                    ov[k] = (v - 0.5f*kvold) + (1.f/12.f)*(av[j][k] + fv);
                } else {
                    au[j][k] += wgt*fu;
                    av[j][k] += wgt*fv;
                    // t_{s+1} = u0 + cadd*k_new, with u0 = t_s - csub*k_prev
                    stu[j][k] = (u - csub*kuold) + cadd*fu;
                    stv[j][k] = (v - csub*kvold) + cadd*fv;
                    ku[j][k] = fu;
                    kv[j][k] = fv;
                }
            }
            if (s == 3) {
                int gr = tr*64 + qrA[j] - 8;          // qr in [8,72) -> [0,64)
                int gc = tc*64 + 4*qcA[j] - 16;       // qc in [4,20) -> [0,64)
                *(f4*)(outu + (size_t)gr*1024 + gc) = ou;  // cached: let L2
                *(f4*)(outv + (size_t)gr*1024 + gc) = ov;  // merge the scatter
            }
        }
        if (s < 3) {
            __syncthreads();   // all reads of t_s done
#pragma unroll
            for (int j = 0; j < NQ; ++j) {
                if (!act[j]) continue;
                *(f4*)(tu+lidx[j]) = stu[j];
                *(f4*)(tv+lidx[j]) = stv[j];
            }
            __syncthreads();   // t_{s+1} visible
        }
    }
}

extern "C" void kernel_launch(void* const* d_in, const int* in_sizes, int n_in,
                              void* d_out, int out_size, void* d_ws, size_t ws_size,
                              hipStream_t stream) {
    const float* h   = (const float*)d_in[0];
    const float* sRe = (const float*)d_in[1];
    const float* sUA = (const float*)d_in[2];
    const float* sUB = (const float*)d_in[3];
    const float* sVA = (const float*)d_in[4];
    const float* sVB = (const float*)d_in[5];
    float* o = (float*)d_out;
    rk4_stencil<<<dim3(16,16,8), dim3(NT,1,1), 0, stream>>>(h, sRe, sUA, sUB, sVA, sVB, o);
}

// Round 5
// 211.932 us; speedup vs baseline: 1.0193x; 1.0193x over previous
//
#include <hip/hip_runtime.h>

// Fused RK4 step for 2D Burgers-like PDE, periodic BCs, radius-2 stencils.
// R7: dense-core + ordered-ring ownership (kill masked-lane issue).
//  - Final-stage region (rows [8,72) x qc [4,20) = 1024 quads) = "dense core":
//    one quad per thread, wave = 4 rows x 16 qc, ACTIVE AT ALL 4 STAGES with
//    no predicate. Ring (496 halo quads) -> tids 0..495, ordered by death
//    stage (s2-survivors [200], s1 [72], s0-only [224]) so per-stage activity
//    is one compare: tid < {496,272,200,0}. Wave-bodies/block: 100 -> 81.
//  - LCOLS=100 bank-perfect layout, async global_load_lds staging (32 uniform
//    1024B chunks/field), center-in-register across stages  [R5/R6, valid].
//  - __launch_bounds__(1024,4); VGPR must stay <=64 for 2 blocks/CU.

typedef float f4 __attribute__((ext_vector_type(4)));
typedef float f2 __attribute__((ext_vector_type(2)));

#define LCOLS 100           // output cols at staged cols [16,80)
#define NFLD  8192          // 80*100 = 8000 staged + 192 dead tail (chunk pad)
#define NT    1024

#define GLOAD16(gp, lp) __builtin_amdgcn_global_load_lds(                      \
    (const __attribute__((address_space(1))) void*)(gp),                       \
    (__attribute__((address_space(3))) void*)(lp), 16, 0, 0)

// One quad (4 cells) of one RK stage. S=0 reads center from LDS; S>=1 uses the
// in-register center su/sv (= previous stage's write-back value). S==3 emits
// the final output into ou/ov instead of updating state.
template<int S>
__device__ __forceinline__ void quad_stage(
    const float* tu, const float* tv, int l,
    float nu, float UA, float UB, float VA, float VB,
    f4& ku, f4& kv, f4& au, f4& av, f4& su, f4& sv, f4& ou, f4& ov)
{
    const float csub = (S==0) ? 0.f : ((S==3) ? 0.5f : 0.25f);
    const float cadd = (S<=1) ? 0.25f : ((S==2) ? 0.5f : 0.f);
    const float wgt  = (S==1 || S==2) ? 2.f : 1.f;
    const float d1 = 800.f/12.f;          // (8/12)/DX
    const float d2 = 100.f/12.f;          // (1/12)/DX
    const float a1 = (4.f/3.f)*1.0e4f;    // (4/3)/DX^2
    const float a2 = -(1.f/12.f)*1.0e4f;  // (-1/12)/DX^2
    const float a0 = -5.0e4f;             // -5/DX^2 (both axes center)

    f4 ucc, vcc;
    if (S == 0) { ucc = *(const f4*)(tu+l); vcc = *(const f4*)(tv+l); }
    else        { ucc = su;                 vcc = sv; }
    f2 ul2 = *(const f2*)(tu+l-2);
    f2 ur2 = *(const f2*)(tu+l+4);
    f4 un1 = *(const f4*)(tu+l-LCOLS);
    f4 us1 = *(const f4*)(tu+l+LCOLS);
    f4 un2 = *(const f4*)(tu+l-2*LCOLS);
    f4 us2 = *(const f4*)(tu+l+2*LCOLS);
    f2 vl2 = *(const f2*)(tv+l-2);
    f2 vr2 = *(const f2*)(tv+l+4);
    f4 vn1 = *(const f4*)(tv+l-LCOLS);
    f4 vs1 = *(const f4*)(tv+l+LCOLS);
    f4 vn2 = *(const f4*)(tv+l-2*LCOLS);
    f4 vs2 = *(const f4*)(tv+l+2*LCOLS);
    float hu[8] = {ul2[0],ul2[1],ucc[0],ucc[1],ucc[2],ucc[3],ur2[0],ur2[1]};
    float hv[8] = {vl2[0],vl2[1],vcc[0],vcc[1],vcc[2],vcc[3],vr2[0],vr2[1]};
#pragma unroll
    for (int k = 0; k < 4; ++k) {
        float u = hu[k+2], v = hv[k+2];
        // row-direction derivative (axis 2) = reference K_DX
        float urow = d1*(us1[k]-un1[k]) + d2*(un2[k]-us2[k]);
        float vrow = d1*(vs1[k]-vn1[k]) + d2*(vn2[k]-vs2[k]);
        // col-direction derivative (axis 3) = reference K_DY
        float ucol = d1*(hu[k+3]-hu[k+1]) + d2*(hu[k]-hu[k+4]);
        float vcol = d1*(hv[k+3]-hv[k+1]) + d2*(hv[k]-hv[k+4]);
        float ulap = a1*((un1[k]+us1[k])+(hu[k+1]+hu[k+3]))
                   + a2*((un2[k]+us2[k])+(hu[k]+hu[k+4])) + a0*u;
        float vlap = a1*((vn1[k]+vs1[k])+(hv[k+1]+hv[k+3]))
                   + a2*((vn2[k]+vs2[k])+(hv[k]+hv[k+4])) + a0*v;
        float fu = nu*ulap + UA*(u*urow) + UB*(v*ucol);
        float fv = nu*vlap + VA*(u*vrow) + VB*(v*vcol);
        float kuold = ku[k], kvold = kv[k];
        if (S == 3) {
            // u0 = t3 - DT*k3 ; out = u0 + (DT/6)*(k1+2k2+2k3+k4)
            ou[k] = (u - 0.5f*kuold) + (1.f/12.f)*(au[k] + fu);
            ov[k] = (v - 0.5f*kvold) + (1.f/12.f)*(av[k] + fv);
        } else {
            au[k] += wgt*fu;
            av[k] += wgt*fv;
            // t_{s+1} = u0 + cadd*k_new, with u0 = t_s - csub*k_prev
            su[k] = (u - csub*kuold) + cadd*fu;
            sv[k] = (v - csub*kvold) + cadd*fv;
            ku[k] = fu;
            kv[k] = fv;
        }
    }
}

__global__ __launch_bounds__(NT, 4)
void rk4_stencil(const float* __restrict__ h,
                 const float* __restrict__ sRe, const float* __restrict__ sUA,
                 const float* __restrict__ sUB, const float* __restrict__ sVA,
                 const float* __restrict__ sVB, float* __restrict__ out)
{
    __shared__ __align__(16) float tu[NFLD];
    __shared__ __align__(16) float tv[NFLD];

    const int tid = threadIdx.x;
    const int tc = blockIdx.x, tr = blockIdx.y, bb = blockIdx.z;

    const float Re = sRe[0], UA = sUA[0], UB = sUB[0], VA = sVA[0], VB = sVB[0];
    const float nu = 0.001f / Re;
    const f4 z4 = {0.f, 0.f, 0.f, 0.f};

    const size_t plane = 1048576;
    const float* uin = h + (size_t)(bb*2) * plane;
    const float* vin = uin + plane;
    const int base_r = tr*64 - 8  + 1024;   // pre-biased for & 1023 wrap
    const int base_c = tc*64 - 16 + 1024;   // multiple of 4 -> no f4 straddle

    // ---- async stage u0,v0: 2 fields x 32 chunks x 1024B, no predicates ----
    // chunk tail (idx >= 8000) stages wrapped-garbage rows 80/81: never read.
    {
        const int wave = tid >> 6, lane = tid & 63;
#pragma unroll
        for (int it = 0; it < 4; ++it) {
            int c = wave + 16*it;           // wave-uniform chunk id 0..63
            int fld = (c >= 32);
            int cc  = c & 31;
            int idx = 256*cc + 4*lane;      // float index into 80x100 tile
            int row = idx / LCOLS;
            int col = idx - row*LCOLS;      // multiple of 4
            int gr = (base_r + row) & 1023;
            int gc = (base_c + col) & 1023;
            const float* gp = (fld ? vin : uin) + ((size_t)gr << 10) + gc;
            float* lp = (fld ? tv : tu) + 256*cc;   // wave-uniform LDS base
            GLOAD16(gp, lp);
        }
    }
    __syncthreads();   // drains vmcnt -> tile visible

    // ---- ownership ----
    // Dense core: rows [8,72) x qc [4,20); wave = 4 rows x 16 qc; active at
    // ALL stages (final region == core), no predicates ever.
    const int wv = tid >> 6, ln = tid & 63;
    const int dqr = 8 + 4*wv + (ln >> 4);
    const int dqc = 4 + (ln & 15);
    const int dl  = dqr*LCOLS + 4*dqc;

    // Ring: 496 halo quads ordered by death stage:
    //  [0,200):  region(s2)\core   (active s0,s1,s2)
    //  [200,272): region(s1)\region(s2)  (active s0,s1)
    //  [272,496): region(s0)\region(s1)  (active s0)
    int rqr = 0, rqc = 0;
    if (tid < 496) {
        int i = tid;
        if      (i < 36)  { rqr = 6  + i/18;       rqc = 3 + i%18; }
        else if (i < 72)  { int t=i-36;  rqr = 72 + t/18; rqc = 3 + t%18; }
        else if (i < 136) { rqr = 8 + (i-72);      rqc = 3; }
        else if (i < 200) { rqr = 8 + (i-136);     rqc = 20; }
        else if (i < 236) { int t=i-200; rqr = 4  + t/18; rqc = 3 + t%18; }
        else if (i < 272) { int t=i-236; rqr = 74 + t/18; rqc = 3 + t%18; }
        else if (i < 312) { int t=i-272; rqr = 2  + t/20; rqc = 2 + t%20; }
        else if (i < 352) { int t=i-312; rqr = 76 + t/20; rqc = 2 + t%20; }
        else if (i < 424) { rqr = 4 + (i-352);     rqc = 2; }
        else              { rqr = 4 + (i-424);     rqc = 21; }
    }
    const int rl = rqr*LCOLS + 4*rqc;

    f4 dku=z4, dkv=z4, dau=z4, dav=z4, dsu=z4, dsv=z4;
    f4 rku=z4, rkv=z4, rau=z4, rav=z4, rsu=z4, rsv=z4;
    f4 du0=z4, du1=z4;   // dummies for S<3 output slots

    // ---- stage 0 (ring active: tid < 496) ----
    quad_stage<0>(tu,tv,dl, nu,UA,UB,VA,VB, dku,dkv,dau,dav,dsu,dsv, du0,du1);
    if (tid < 496)
        quad_stage<0>(tu,tv,rl, nu,UA,UB,VA,VB, rku,rkv,rau,rav,rsu,rsv, du0,du1);
    __syncthreads();
    *(f4*)(tu+dl) = dsu; *(f4*)(tv+dl) = dsv;
    if (tid < 496) { *(f4*)(tu+rl) = rsu; *(f4*)(tv+rl) = rsv; }
    __syncthreads();

    // ---- stage 1 (ring active: tid < 272) ----
    quad_stage<1>(tu,tv,dl, nu,UA,UB,VA,VB, dku,dkv,dau,dav,dsu,dsv, du0,du1);
    if (tid < 272)
        quad_stage<1>(tu,tv,rl, nu,UA,UB,VA,VB, rku,rkv,rau,rav,rsu,rsv, du0,du1);
    __syncthreads();
    *(f4*)(tu+dl) = dsu; *(f4*)(tv+dl) = dsv;
    if (tid < 272) { *(f4*)(tu+rl) = rsu; *(f4*)(tv+rl) = rsv; }
    __syncthreads();

    // ---- stage 2 (ring active: tid < 200) ----
    quad_stage<2>(tu,tv,dl, nu,UA,UB,VA,VB, dku,dkv,dau,dav,dsu,dsv, du0,du1);
    if (tid < 200)
        quad_stage<2>(tu,tv,rl, nu,UA,UB,VA,VB, rku,rkv,rau,rav,rsu,rsv, du0,du1);
    __syncthreads();
    *(f4*)(tu+dl) = dsu; *(f4*)(tv+dl) = dsv;
    if (tid < 200) { *(f4*)(tu+rl) = rsu; *(f4*)(tv+rl) = rsv; }
    __syncthreads();

    // ---- stage 3 (dense only; direct global store) ----
    {
        float* outu = out + (size_t)(bb*2) * plane;
        float* outv = outu + plane;
        f4 ou, ov;
        quad_stage<3>(tu,tv,dl, nu,UA,UB,VA,VB, dku,dkv,dau,dav,dsu,dsv, ou,ov);
        int gr = tr*64 + (dqr - 8);        // [0,64)
        int gc = tc*64 + 4*dqc - 16;       // [0,64), 16 lanes = 256B contiguous
        *(f4*)(outu + (size_t)gr*1024 + gc) = ou;
        *(f4*)(outv + (size_t)gr*1024 + gc) = ov;
    }
}

extern "C" void kernel_launch(void* const* d_in, const int* in_sizes, int n_in,
                              void* d_out, int out_size, void* d_ws, size_t ws_size,
                              hipStream_t stream) {
    const float* h   = (const float*)d_in[0];
    const float* sRe = (const float*)d_in[1];
    const float* sUA = (const float*)d_in[2];
    const float* sUB = (const float*)d_in[3];
    const float* sVA = (const float*)d_in[4];
    const float* sVB = (const float*)d_in[5];
    float* o = (float*)d_out;
    rk4_stencil<<<dim3(16,16,8), dim3(NT,1,1), 0, stream>>>(h, sRe, sUA, sUB, sVA, sVB, o);
}